// Round 8
// baseline (101.356 us; speedup 1.0000x reference)
//
#include <hip/hip_runtime.h>

// Problem: y = x * exp(S)[None,:]  (B=65536, D=1024, f32)
//          det_out = original_det + sum(S)
// d_out layout: [ y (B*D f32) | det_out (B f32) ]
//
// Round-7 structure (91.0us best): 8192 blocks x 256 threads, each block owns
// a CONTIGUOUS 2048-float4 chunk (32 KB r + 32 KB w), 8-deep load batch
// issued before the exp prologue (8 outstanding 16B loads/lane); log_det
// reduction + barrier confined to the 64 det-writing blocks.
// ONE change vs round 7: NO nontemporal hints -- plain global loads/stores
// (A/B test: nt bit may throttle the sequential read stream's L2 behavior).

typedef float f32x4 __attribute__((ext_vector_type(4)));

#define DEPTH 8

__global__ __launch_bounds__(256) void fused_kernel(
    const f32x4* __restrict__ x,
    const f32x4* __restrict__ det,
    const f32x4* __restrict__ S4,      // D/4 float4
    f32x4* __restrict__ y,
    f32x4* __restrict__ det_out,
    size_t nvec,                       // B*D/4
    int    dvec)                       // B/4
{
    const int tid = threadIdx.x;
    const size_t base = (size_t)blockIdx.x * (256 * DEPTH) + tid;

    // --- issue all 8 x-loads first (independent of S) ---
    f32x4 r[DEPTH];
    const bool full = (base + (DEPTH - 1) * 256) < nvec;
    if (full) {
#pragma unroll
        for (int k = 0; k < DEPTH; ++k)
            r[k] = x[base + (size_t)k * 256];
    }

    // --- per-thread exp(S) factor (overlaps load latency) ---
    f32x4 s4 = S4[tid];
    f32x4 e4;
    e4.x = expf(s4.x);
    e4.y = expf(s4.y);
    e4.z = expf(s4.z);
    e4.w = expf(s4.w);

    // --- multiply + store ---
    if (full) {
#pragma unroll
        for (int k = 0; k < DEPTH; ++k)
            y[base + (size_t)k * 256] = r[k] * e4;
    } else {
        for (size_t v = base; v < nvec; v += 256) {
            f32x4 xv = x[v];
            y[v] = xv * e4;
        }
    }

    // --- det: only first 64 blocks (uniform branch; barrier is legal) ---
    if (blockIdx.x < 64) {
        __shared__ float red[4];
        float local = s4.x + s4.y + s4.z + s4.w;
        for (int off = 32; off > 0; off >>= 1)
            local += __shfl_down(local, off, 64);
        if ((tid & 63) == 0) red[tid >> 6] = local;
        __syncthreads();
        const float log_det = red[0] + red[1] + red[2] + red[3];

        size_t di = (size_t)blockIdx.x * 256 + tid;
        if (di < (size_t)dvec) {
            f32x4 d = det[di];
            det_out[di] = d + log_det;
        }
    }
}

extern "C" void kernel_launch(void* const* d_in, const int* in_sizes, int n_in,
                              void* d_out, int out_size, void* d_ws, size_t ws_size,
                              hipStream_t stream) {
    const float* x   = (const float*)d_in[0];
    const float* det = (const float*)d_in[1];
    const float* S   = (const float*)d_in[2];

    const int xN = in_sizes[0];      // B*D = 67108864
    const int B  = in_sizes[1];      // 65536

    float* y_out   = (float*)d_out;
    float* det_out = (float*)d_out + (size_t)xN;

    size_t nvec = (size_t)xN / 4;    // 16,777,216 float4
    int    dvec = B / 4;             // 16,384 float4

    // 8192 blocks x 2048 float4/block covers nvec exactly (>= 64 blocks for det).
    int blocks = (int)((nvec + (256 * DEPTH - 1)) / (256 * DEPTH));
    if (blocks < 64) blocks = 64;

    fused_kernel<<<blocks, 256, 0, stream>>>(
        (const f32x4*)x, (const f32x4*)det, (const f32x4*)S,
        (f32x4*)y_out, (f32x4*)det_out, nvec, dvec);
}

// Round 9
// 83.012 us; speedup vs baseline: 1.2210x; 1.2210x over previous
//
#include <hip/hip_runtime.h>

// Problem: y = x * exp(S)[None,:]  (B=65536, D=1024, f32)
//          det_out = original_det + sum(S)
// d_out layout: [ y (B*D f32) | det_out (B f32) ]
//
// Structure = round-7 best (90.97us): 8192 blocks x 256 threads, contiguous
// 2048-float4 chunk per block, 8-deep load batch before the exp prologue,
// log_det + barrier confined to the 64 det-writing blocks.
// ONE change vs round 7: loads are PLAIN (cached), stores stay NONTEMPORAL.
// R8 showed removing both NT hints costs 10%; this isolates load vs store.

typedef float f32x4 __attribute__((ext_vector_type(4)));

#define DEPTH 8

__global__ __launch_bounds__(256) void fused_kernel(
    const f32x4* __restrict__ x,
    const f32x4* __restrict__ det,
    const f32x4* __restrict__ S4,      // D/4 float4
    f32x4* __restrict__ y,
    f32x4* __restrict__ det_out,
    size_t nvec,                       // B*D/4
    int    dvec)                       // B/4
{
    const int tid = threadIdx.x;
    const size_t base = (size_t)blockIdx.x * (256 * DEPTH) + tid;

    // --- issue all 8 x-loads first (independent of S); plain/cached ---
    f32x4 r[DEPTH];
    const bool full = (base + (DEPTH - 1) * 256) < nvec;
    if (full) {
#pragma unroll
        for (int k = 0; k < DEPTH; ++k)
            r[k] = x[base + (size_t)k * 256];
    }

    // --- per-thread exp(S) factor (overlaps load latency) ---
    f32x4 s4 = S4[tid];
    f32x4 e4;
    e4.x = expf(s4.x);
    e4.y = expf(s4.y);
    e4.z = expf(s4.z);
    e4.w = expf(s4.w);

    // --- multiply + store (nontemporal: don't pollute L2 with y) ---
    if (full) {
#pragma unroll
        for (int k = 0; k < DEPTH; ++k)
            __builtin_nontemporal_store(r[k] * e4, &y[base + (size_t)k * 256]);
    } else {
        for (size_t v = base; v < nvec; v += 256) {
            f32x4 xv = x[v];
            __builtin_nontemporal_store(xv * e4, &y[v]);
        }
    }

    // --- det: only first 64 blocks (uniform branch; barrier is legal) ---
    if (blockIdx.x < 64) {
        __shared__ float red[4];
        float local = s4.x + s4.y + s4.z + s4.w;
        for (int off = 32; off > 0; off >>= 1)
            local += __shfl_down(local, off, 64);
        if ((tid & 63) == 0) red[tid >> 6] = local;
        __syncthreads();
        const float log_det = red[0] + red[1] + red[2] + red[3];

        size_t di = (size_t)blockIdx.x * 256 + tid;
        if (di < (size_t)dvec) {
            f32x4 d = det[di];
            __builtin_nontemporal_store(d + log_det, &det_out[di]);
        }
    }
}

extern "C" void kernel_launch(void* const* d_in, const int* in_sizes, int n_in,
                              void* d_out, int out_size, void* d_ws, size_t ws_size,
                              hipStream_t stream) {
    const float* x   = (const float*)d_in[0];
    const float* det = (const float*)d_in[1];
    const float* S   = (const float*)d_in[2];

    const int xN = in_sizes[0];      // B*D = 67108864
    const int B  = in_sizes[1];      // 65536

    float* y_out   = (float*)d_out;
    float* det_out = (float*)d_out + (size_t)xN;

    size_t nvec = (size_t)xN / 4;    // 16,777,216 float4
    int    dvec = B / 4;             // 16,384 float4

    // 8192 blocks x 2048 float4/block covers nvec exactly (>= 64 blocks for det).
    int blocks = (int)((nvec + (256 * DEPTH - 1)) / (256 * DEPTH));
    if (blocks < 64) blocks = 64;

    fused_kernel<<<blocks, 256, 0, stream>>>(
        (const f32x4*)x, (const f32x4*)det, (const f32x4*)S,
        (f32x4*)y_out, (f32x4*)det_out, nvec, dvec);
}